// Round 8
// baseline (33874.976 us; speedup 1.0000x reference)
//
#include <hip/hip_runtime.h>

typedef _Float16 f16;
typedef _Float16 f16x8 __attribute__((ext_vector_type(8)));
typedef float f32x4 __attribute__((ext_vector_type(4)));
typedef unsigned int u32x4 __attribute__((ext_vector_type(4)));
typedef long i64;

static constexpr int kS = 1024;   // timesteps
static constexpr float WSCALE = 8192.f;     // 2^13: weights into e4m3 normal range
static constexpr float HSCALE = 64.f;       // 2^6:  h into e4m3 normal range
static constexpr float ZDESCALE = 1.f / (8192.f * 64.f);   // 2^-19

// workspace layout (bytes); total ~26 MB
static constexpr size_t OFF_WP = 0;                        // u8  [8192][2048] fp8 packed gate weights (h part), x WSCALE
static constexpr size_t OFF_WX = 16777216;                 // f32 [8192] column 0 (x weight), unscaled
static constexpr size_t OFF_BB = OFF_WX + 32768;           // f32 [8192] bias, unscaled
static constexpr size_t OFF_XT = OFF_BB + 32768;           // f32 [1024][512] x transposed
static constexpr size_t OFF_H8A = OFF_XT + 2097152;        // u8 [512][2048] h fp8 ping (x HSCALE)
static constexpr size_t OFF_H8B = OFF_H8A + 2097152/2;     // u8 [512][2048] h fp8 pong
static constexpr size_t OFF_HF  = OFF_H8B + 2097152/2;     // f16 [512][2048] final h (written at t=1023)
static constexpr size_t OFF_CB  = OFF_HF + 2097152;        // f32 [256 blk][256 thr][16] cell state

__device__ __forceinline__ void gload16(const void* g, void* l) {
  __builtin_amdgcn_global_load_lds(
      (const __attribute__((address_space(1))) unsigned int*)g,
      (__attribute__((address_space(3))) unsigned int*)l, 16, 0, 0);
}

__device__ __forceinline__ float sigf(float x) { return 1.f / (1.f + __expf(-x)); }
__device__ __forceinline__ float tanh_fast(float x) {
  float e = __expf(2.f * x);
  return 1.f - 2.f / (e + 1.f);   // +-inf safe: -> 1 / -1
}
__device__ __forceinline__ unsigned char to_fp8(float v) {
  return (unsigned char)(__builtin_amdgcn_cvt_pk_fp8_f32(v, 0.f, 0, false) & 0xFF);
}

// Pack W rows into order (unit*4 + gate), fp8 e4m3 scaled by WSCALE, h-columns
// only (cols 1..2048). Row R -> unit u = (R>>8)*64 + ((R&255)>>2), gate = R&3.
__global__ void pack_weights(const float* __restrict__ Wg, const float* __restrict__ Wi,
                             const float* __restrict__ Wf, const float* __restrict__ Wo,
                             const float* __restrict__ bg, const float* __restrict__ bi,
                             const float* __restrict__ bf, const float* __restrict__ bo,
                             unsigned char* __restrict__ Wp, float* __restrict__ wx,
                             float* __restrict__ bb)
{
  const int R = blockIdx.x;
  const int p = R >> 8, r = R & 255;
  const int u = (p << 6) + (r >> 2), gsel = r & 3;
  const float* Wsrc = (gsel == 0) ? Wg : (gsel == 1) ? Wi : (gsel == 2) ? Wf : Wo;
  const float* bsrc = (gsel == 0) ? bg : (gsel == 1) ? bi : (gsel == 2) ? bf : bo;
  const float* src = Wsrc + (size_t)u * 2049;
  const int k = threadIdx.x * 8;
  float v[8];
#pragma unroll
  for (int j = 0; j < 8; ++j) v[j] = src[1 + k + j] * WSCALE;
  int lo = __builtin_amdgcn_cvt_pk_fp8_f32(v[0], v[1], 0, false);
  lo = __builtin_amdgcn_cvt_pk_fp8_f32(v[2], v[3], lo, true);
  int hi2 = __builtin_amdgcn_cvt_pk_fp8_f32(v[4], v[5], 0, false);
  hi2 = __builtin_amdgcn_cvt_pk_fp8_f32(v[6], v[7], hi2, true);
  *(uint2*)(Wp + (size_t)R * 2048 + k) = make_uint2((unsigned)lo, (unsigned)hi2);
  if (threadIdx.x == 0) { wx[R] = src[0]; bb[R] = bsrc[u]; }
}

__global__ void transpose_x(const float* __restrict__ x, float* __restrict__ xT) {
  const int idx = blockIdx.x * 256 + threadIdx.x;   // 512*1024
  const int b = idx >> 10, t = idx & 1023;
  xT[t * 512 + b] = x[idx];
}

__global__ void zero_h(unsigned char* h8) {
  const int idx = blockIdx.x * 256 + threadIdx.x;   // 65536 x 16B = 1MB
  ((uint4*)h8)[idx] = make_uint4(0u, 0u, 0u, 0u);
}

// One LSTM timestep, fp8 operands: 256 blocks x 256 threads; block tile =
// 32 units (128 packed rows) x 128 batch. K-chunk 64 (64 B/row), depth-3 ring,
// two barriers per chunk, counted vmcnt. 16B-block swizzle: LDS block slot b
// of row r holds logical block b^(r&3); un-XOR on ds_read -> logical k-order
// is row-independent (required for MFMA dot-product consistency).
// mfma_f32_16x16x32_fp8_fp8: frag = 8 fp8 (i64); thread's 4 acc regs = one
// unit's (g,i,f,o). acc descaled by 2^-19 in epilogue.
__global__ __launch_bounds__(256, 1) void lstm_step(
    const unsigned char* __restrict__ Wp, const float* __restrict__ wx,
    const float* __restrict__ bb, const float* __restrict__ xT,
    const unsigned char* __restrict__ hin, unsigned char* __restrict__ hout,
    f16* __restrict__ hF, float* __restrict__ cbuf, int t)
{
  extern __shared__ __align__(16) char smem[];
  unsigned char* ldsA = (unsigned char*)smem;            // [3][128][64] (24 KB)
  unsigned char* ldsB = (unsigned char*)(smem + 24576);  // [3][128][64] (24 KB)
  unsigned char* ldsH = (unsigned char*)smem;            // [128][48] h-out fp8 tile, aliases ring slot 0

  const int blk = blockIdx.x;
  // XCD affinity: the 4 batch-panels sharing a weight panel have the same blk%8.
  const int p  = (blk & 7) + 8 * (blk >> 5);           // weight panel 0..63
  const int bp = (blk >> 3) & 3;                        // batch panel 0..3
  const int u0 = p * 32, b0 = bp * 128;

  const int tid = threadIdx.x;
  const int w = tid >> 6, l = tid & 63;
  const int wr = w >> 1, wc = w & 1;
  const int l15 = l & 15, hi = l >> 4;
  // staging: lane l covers row rowbase+(l>>2), 16B block (l&3); source block
  // pre-XOR'd by r&3 = (l>>2)&3 (rowbase % 16 == 0).
  const int lrow = l >> 2;
  const int kblk = ((l & 3) ^ (lrow & 3)) * 16;

  // per-thread row constants: x-weight and bias for 4 subtiles x 4 gates
  float wxr[4][4], br[4][4];
#pragma unroll
  for (int ni = 0; ni < 4; ++ni)
#pragma unroll
    for (int r = 0; r < 4; ++r) {
      const int R = p * 128 + wr * 64 + ni * 16 + hi * 4 + r;
      wxr[ni][r] = wx[R];
      br[ni][r] = bb[R];
    }

  // x_t for this thread's 4 batch columns
  float xv[4];
#pragma unroll
  for (int bj = 0; bj < 4; ++bj)
    xv[bj] = xT[t * 512 + b0 + wc * 64 + bj * 16 + l15];

  // cell state: per-thread contiguous, NT (zero reuse within a step)
  float* cme = cbuf + ((size_t)blk * 256 + tid) * 16;
  float cst[4][4];
  if (t == 0) {
#pragma unroll
    for (int ni = 0; ni < 4; ++ni)
#pragma unroll
      for (int bj = 0; bj < 4; ++bj) cst[ni][bj] = 0.f;
  } else {
#pragma unroll
    for (int ni = 0; ni < 4; ++ni) {
      const f32x4 cv = __builtin_nontemporal_load((const f32x4*)(cme + ni * 4));
      cst[ni][0] = cv[0]; cst[ni][1] = cv[1]; cst[ni][2] = cv[2]; cst[ni][3] = cv[3];
    }
  }

  // stage chunk ch (K cols [ch*64, +64) fp8) into ring slot: 4 gload16/thread
  // stream (A 2 + B 2; each instr = 16 rows x 64 B).
  auto stage = [&](int ch, int slot) {
    const size_t kof = (size_t)ch * 64 + kblk;
#pragma unroll
    for (int j = 0; j < 2; ++j) {
      const int rowbase = w * 32 + j * 16;
      gload16(Wp + (size_t)(p * 128 + rowbase + lrow) * 2048 + kof,
              ldsA + slot * 8192 + rowbase * 64);
    }
#pragma unroll
    for (int j = 0; j < 2; ++j) {
      const int rowbase = w * 32 + j * 16;
      gload16(hin + (size_t)(b0 + rowbase + lrow) * 2048 + kof,
              ldsB + slot * 8192 + rowbase * 64);
    }
  };

  f32x4 acc[4][4];
#pragma unroll
  for (int ni = 0; ni < 4; ++ni)
#pragma unroll
    for (int bj = 0; bj < 4; ++bj)
      acc[ni][bj] = (f32x4){0.f, 0.f, 0.f, 0.f};

  // prologue: fill 2 of 3 ring slots (8 gloads outstanding)
  stage(0, 0); stage(1, 1);

  int bufc = 0;    // slot consumed = ch % 3
#pragma unroll 1
  for (int ch = 0; ch < 32; ++ch) {
    if (ch < 30) {
      int sslot = bufc - 1; if (sslot < 0) sslot = 2;    // (ch+2) % 3
      stage(ch + 2, sslot);
      asm volatile("s_waitcnt vmcnt(8)" ::: "memory");   // chunk ch landed
    } else if (ch == 30) {
      asm volatile("s_waitcnt vmcnt(4)" ::: "memory");
    } else {
      asm volatile("s_waitcnt vmcnt(0)" ::: "memory");
    }
    __builtin_amdgcn_sched_barrier(0);
    __builtin_amdgcn_s_barrier();        // all waves' chunk-ch data in LDS
    __builtin_amdgcn_sched_barrier(0);

    const unsigned char* A  = ldsA + bufc * 8192;
    const unsigned char* Bm = ldsB + bufc * 8192;
#pragma unroll
    for (int ks = 0; ks < 2; ++ks) {
      const int kk = ks * 4 + hi;                        // logical 8B k-slot 0..7
      i64 af[4], bfr[4];
#pragma unroll
      for (int ni = 0; ni < 4; ++ni) {
        const int r = wr * 64 + ni * 16 + l15;
        af[ni] = *(const i64*)(A + r * 64 + (((kk >> 1) ^ (r & 3)) << 4) + ((kk & 1) << 3));
      }
#pragma unroll
      for (int bj = 0; bj < 4; ++bj) {
        const int r = wc * 64 + bj * 16 + l15;
        bfr[bj] = *(const i64*)(Bm + r * 64 + (((kk >> 1) ^ (r & 3)) << 4) + ((kk & 1) << 3));
      }
#pragma unroll
      for (int ni = 0; ni < 4; ++ni)
#pragma unroll
        for (int bj = 0; bj < 4; ++bj)
          acc[ni][bj] = __builtin_amdgcn_mfma_f32_16x16x32_fp8_fp8(af[ni], bfr[bj], acc[ni][bj], 0, 0, 0);
    }

    __builtin_amdgcn_sched_barrier(0);
    __builtin_amdgcn_s_barrier();        // everyone done reading slot bufc
    bufc = (bufc == 2) ? 0 : bufc + 1;
  }

  // epilogue: descale, cell update (register-local: acc regs = one unit's gifo)
#pragma unroll
  for (int ni = 0; ni < 4; ++ni) {
    f32x4 cnew;
#pragma unroll
    for (int bj = 0; bj < 4; ++bj) {
      const f32x4 a = acc[ni][bj];
      const float z0 = a[0] * ZDESCALE + br[ni][0] + xv[bj] * wxr[ni][0];
      const float z1 = a[1] * ZDESCALE + br[ni][1] + xv[bj] * wxr[ni][1];
      const float z2 = a[2] * ZDESCALE + br[ni][2] + xv[bj] * wxr[ni][2];
      const float z3 = a[3] * ZDESCALE + br[ni][3] + xv[bj] * wxr[ni][3];
      const float gg = tanh_fast(z0);
      const float ig = sigf(z1);
      const float fg = sigf(z2);
      const float og = sigf(z3);
      const float cc = gg * ig + cst[ni][bj] * fg;
      cnew[bj] = cc;
      const float hh = tanh_fast(cc) * og;
      const int row = wc * 64 + bj * 16 + l15;          // batch-local
      const int ucol = wr * 16 + ni * 4 + hi;           // unit-local
      ldsH[row * 48 + ucol] = to_fp8(hh * HSCALE);
      if (t == kS - 1)
        hF[(size_t)(b0 + row) * 2048 + u0 + ucol] = (f16)hh;
    }
    __builtin_nontemporal_store(cnew, (f32x4*)(cme + ni * 4));
  }
  __syncthreads();

  // coalesced h-tile writeout: 128 rows x 32 B, 1 x 16B per thread
  {
    const int row = tid >> 1, half = tid & 1;
    const u32x4 v = *(const u32x4*)(ldsH + row * 48 + half * 16);
    __builtin_nontemporal_store(v, (u32x4*)(hout + (size_t)(b0 + row) * 2048 + u0 + half * 16));
  }
}

// y[b][o] = sum_k h[b][k]*Wy[o][k] + by[o]  (one-shot, fp32, reads f16 final h)
__global__ void out_proj(const f16* __restrict__ h, const float* __restrict__ Wy,
                         const float* __restrict__ by, float* __restrict__ y)
{
  const int gi = blockIdx.x * 256 + threadIdx.x;   // 65536
  const int o = gi & 127, b = gi >> 7;
  const f16* hr = h + (size_t)b * 2048;
  const float* wr = Wy + (size_t)o * 2048;
  float acc = 0.f;
  for (int k = 0; k < 2048; k += 8) {
    const f16x8 hv = *(const f16x8*)(hr + k);
    const float4 wa = *(const float4*)(wr + k);
    const float4 wb = *(const float4*)(wr + k + 4);
    acc += (float)hv[0] * wa.x + (float)hv[1] * wa.y + (float)hv[2] * wa.z + (float)hv[3] * wa.w
         + (float)hv[4] * wb.x + (float)hv[5] * wb.y + (float)hv[6] * wb.z + (float)hv[7] * wb.w;
  }
  y[gi] = acc + by[o];
}

extern "C" void kernel_launch(void* const* d_in, const int* in_sizes, int n_in,
                              void* d_out, int out_size, void* d_ws, size_t ws_size,
                              hipStream_t stream)
{
  const float* x  = (const float*)d_in[0];
  const float* Wg = (const float*)d_in[1];
  const float* bg = (const float*)d_in[2];
  const float* Wi = (const float*)d_in[3];
  const float* bi = (const float*)d_in[4];
  const float* Wf = (const float*)d_in[5];
  const float* bf = (const float*)d_in[6];
  const float* Wo = (const float*)d_in[7];
  const float* bo = (const float*)d_in[8];
  const float* Wy = (const float*)d_in[9];
  const float* by = (const float*)d_in[10];
  float* y = (float*)d_out;

  char* ws = (char*)d_ws;
  unsigned char* Wp  = (unsigned char*)(ws + OFF_WP);
  float* wx = (float*)(ws + OFF_WX);
  float* bb = (float*)(ws + OFF_BB);
  float* xT = (float*)(ws + OFF_XT);
  unsigned char* h8A = (unsigned char*)(ws + OFF_H8A);
  unsigned char* h8B = (unsigned char*)(ws + OFF_H8B);
  f16*   hF = (f16*)(ws + OFF_HF);
  float* cb = (float*)(ws + OFF_CB);

  pack_weights<<<8192, 256, 0, stream>>>(Wg, Wi, Wf, Wo, bg, bi, bf, bo, Wp, wx, bb);
  transpose_x<<<2048, 256, 0, stream>>>(x, xT);
  zero_h<<<256, 256, 0, stream>>>(h8A);

  (void)hipFuncSetAttribute((const void*)lstm_step,
                            hipFuncAttributeMaxDynamicSharedMemorySize, 65536);
  for (int t = 0; t < kS; ++t) {
    const unsigned char* hin = (t & 1) ? h8B : h8A;
    unsigned char*      hout = (t & 1) ? h8A : h8B;
    lstm_step<<<256, 256, 49152, stream>>>(Wp, wx, bb, xT, hin, hout, hF, cb, t);
  }

  out_proj<<<256, 256, 0, stream>>>(hF, Wy, by, y);
}